// Round 13
// baseline (473.048 us; speedup 1.0000x reference)
//
#include <hip/hip_runtime.h>
#include <hip/hip_bf16.h>

#define SEQ   4096
#define NFFT  8192
#define NCH   768
#define NB    16
#define KGST  4104            // Kg row stride in uint2 units (4096 bins + pad)
#define LDSN  4368            // phys(4095)=4365

// Twiddle table layout (f4 units): F1[15][256] @0, I1 @3840, F2[15][16] @7680,
// I2 @7920; entry = {w.x, w.y, iw.x, iw.y}, iw = i*w. Total 8160 f4 = 130,560 B.
#define TW_F1 0
#define TW_I1 3840
#define TW_F2 7680
#define TW_I2 7920

// packed complex float: clang lowers +,-,* to v_pk_{add,mul,fma}_f32 on gfx950
typedef float cf __attribute__((ext_vector_type(2)));
typedef float f4 __attribute__((ext_vector_type(4)));

// padding spreads both stride-16 (->17) and stride-256 (->273) lane patterns
__device__ __forceinline__ int phys(int p) { return p + (p >> 4) + (p >> 8); }
__device__ __forceinline__ int br12(int k) { return (int)(__brev((unsigned)k) >> 20); }

// phys() is affine over each pass's access set base + m*G (no carries into
// bits 4/8): phys(base + m*G) = phys(base) + m*step(G).
constexpr int stepFor(int G) { return G == 256 ? 273 : (G == 16 ? 17 : 1); }

// constexpr so BR4[r] folds at compile time -> v[] statically indexed -> regs
constexpr int BR4[16] = {0,8,4,12,2,10,6,14,1,9,5,13,3,11,7,15};

// a*w given iw = i*w:  r = a.xx*w + a.yy*iw  -> pk_mul + pk_fma
__device__ __forceinline__ cf cmul_wi(cf a, cf w, cf iw) {
  cf axx = __builtin_shufflevector(a, a, 0, 0);
  cf ayy = __builtin_shufflevector(a, a, 1, 1);
  return axx * w + ayy * iw;
}
__device__ __forceinline__ cf icmul(cf a) { return cf{-a.y, a.x}; }  // i*a
__device__ __forceinline__ cf cmul(cf a, cf b) { return cmul_wi(a, b, icmul(b)); }
// a * conj(z)
__device__ __forceinline__ cf cmul_cj(cf a, cf z) {
  return cmul_wi(a, cf{z.x, -z.y}, cf{z.y, z.x});
}

#define CMULC(a, WX, WY) cmul_wi(a, cf{(WX),(WY)}, cf{-(WY),(WX)})

#define C1X 0.9238795325112867f
#define C1Y (-0.3826834323650898f)
#define C2X 0.7071067811865476f
#define C2Y (-0.7071067811865476f)
#define C3X 0.3826834323650898f
#define C3Y (-0.9238795325112867f)

#define BF_F(a, b, WX, WY) { cf t_ = a - b; a = a + b; b = CMULC(t_, WX, WY); }
#define BF_F1(a, b)        { cf t_ = a - b; a = a + b; b = t_; }
#define BF_FJ(a, b)        { cf t_ = a - b; a = a + b; b = cf{t_.y, -t_.x}; }
#define BF_I(a, b, WX, WY) { cf t_ = cmul_wi(b, cf{(WX),-(WY)}, cf{(WY),(WX)}); b = a - t_; a = a + t_; }
#define BF_I1(a, b)        { cf t_ = b; b = a - t_; a = a + t_; }
#define BF_IJ(a, b)        { cf t_ = cf{-b.y, b.x}; b = a - t_; a = a + t_; }

__device__ __forceinline__ void dft16_f_tail(cf v[16]) {
  BF_F1(v[0], v[4]);            BF_F(v[1], v[5],  C2X, C2Y);
  BF_FJ(v[2], v[6]);            BF_F(v[3], v[7], -C2X, C2Y);
  BF_F1(v[8], v[12]);           BF_F(v[9], v[13], C2X, C2Y);
  BF_FJ(v[10], v[14]);          BF_F(v[11], v[15], -C2X, C2Y);
  BF_F1(v[0], v[2]);  BF_FJ(v[1], v[3]);
  BF_F1(v[4], v[6]);  BF_FJ(v[5], v[7]);
  BF_F1(v[8], v[10]); BF_FJ(v[9], v[11]);
  BF_F1(v[12], v[14]); BF_FJ(v[13], v[15]);
  BF_F1(v[0], v[1]);  BF_F1(v[2], v[3]);
  BF_F1(v[4], v[5]);  BF_F1(v[6], v[7]);
  BF_F1(v[8], v[9]);  BF_F1(v[10], v[11]);
  BF_F1(v[12], v[13]); BF_F1(v[14], v[15]);
}

__device__ __forceinline__ void dft16_f(cf v[16]) {
  BF_F1(v[0], v[8]);
  BF_F(v[1], v[9],  C1X, C1Y);
  BF_F(v[2], v[10], C2X, C2Y);
  BF_F(v[3], v[11], C3X, C3Y);
  BF_FJ(v[4], v[12]);
  BF_F(v[5], v[13], -C3X, C3Y);
  BF_F(v[6], v[14], -C2X, C2Y);
  BF_F(v[7], v[15], -C1X, C1Y);
  dft16_f_tail(v);
}

__device__ __forceinline__ void dft16_i(cf v[16]) {
  BF_I1(v[0], v[1]);  BF_I1(v[2], v[3]);
  BF_I1(v[4], v[5]);  BF_I1(v[6], v[7]);
  BF_I1(v[8], v[9]);  BF_I1(v[10], v[11]);
  BF_I1(v[12], v[13]); BF_I1(v[14], v[15]);
  BF_I1(v[0], v[2]);  BF_IJ(v[1], v[3]);
  BF_I1(v[4], v[6]);  BF_IJ(v[5], v[7]);
  BF_I1(v[8], v[10]); BF_IJ(v[9], v[11]);
  BF_I1(v[12], v[14]); BF_IJ(v[13], v[15]);
  BF_I1(v[0], v[4]);            BF_I(v[1], v[5],  C2X, C2Y);
  BF_IJ(v[2], v[6]);            BF_I(v[3], v[7], -C2X, C2Y);
  BF_I1(v[8], v[12]);           BF_I(v[9], v[13], C2X, C2Y);
  BF_IJ(v[10], v[14]);          BF_I(v[11], v[15], -C2X, C2Y);
  BF_I1(v[0], v[8]);
  BF_I(v[1], v[9],  C1X, C1Y);
  BF_I(v[2], v[10], C2X, C2Y);
  BF_I(v[3], v[11], C3X, C3Y);
  BF_IJ(v[4], v[12]);
  BF_I(v[5], v[13], -C3X, C3Y);
  BF_I(v[6], v[14], -C2X, C2Y);
  BF_I(v[7], v[15], -C1X, C1Y);
}

// chain twiddle (filter kernel only — tables not ready during filter)
__device__ __forceinline__ void twiddle_chain(cf v[16], cf w1) {
  cf iw1 = icmul(w1);
  cf wr = w1, iwr = iw1;
  #pragma unroll
  for (int r = 1; r < 16; ++r) {
    v[BR4[r]] = cmul_wi(v[BR4[r]], wr, iwr);
    if (r < 15) { wr = cmul_wi(wr, w1, iw1); iwr = icmul(wr); }
  }
}
__device__ __forceinline__ void twiddle_f_chain(cf v[16], int i, float invNP) {
  float sn, cs; __sincosf(-6.283185307179586f * (float)i * invNP, &sn, &cs);
  twiddle_chain(v, cf{cs, sn});
}
__device__ __forceinline__ void twiddle_i_chain(cf v[16], int i, float invNP) {
  float sn, cs; __sincosf(6.283185307179586f * (float)i * invNP, &sn, &cs);
  twiddle_chain(v, cf{cs, sn});
}

// table twiddle (conv kernel): 15 coalesced f4 loads replace sincos + chain
template<int STRIDE>
__device__ __forceinline__ void twiddle_tbl(cf v[16], const f4* __restrict__ tw, int i) {
  #pragma unroll
  for (int r = 1; r < 16; ++r) {
    f4 t = tw[(r - 1) * STRIDE + i];
    v[BR4[r]] = cmul_wi(v[BR4[r]], cf{t.x, t.y}, cf{t.z, t.w});
  }
}

// first forward pass (NP=4096,G=256), input zero for indices >= 2048;
// touches only the calling thread's own slots {tid + m*256}
template<bool TW>
__device__ __forceinline__ void pass_f_first(cf* X, int tid, const f4* __restrict__ tw) {
  cf* Xp = X + phys(tid);
  cf v[16];
  #pragma unroll
  for (int m = 0; m < 8; ++m) v[m] = Xp[273 * m];
  v[8]  = v[0];
  v[9]  = CMULC(v[1],  C1X, C1Y);
  v[10] = CMULC(v[2],  C2X, C2Y);
  v[11] = CMULC(v[3],  C3X, C3Y);
  v[12] = cf{v[4].y, -v[4].x};
  v[13] = CMULC(v[5], -C3X, C3Y);
  v[14] = CMULC(v[6], -C2X, C2Y);
  v[15] = CMULC(v[7], -C1X, C1Y);
  dft16_f_tail(v);
  if (TW) twiddle_tbl<256>(v, tw + TW_F1, tid);
  else if (tid) twiddle_f_chain(v, tid, 1.0f / 4096.0f);
  #pragma unroll
  for (int s = 0; s < 16; ++s) Xp[273 * s] = v[s];
}

template<int NP, bool TW>
__device__ __forceinline__ void pass_f(cf* X, int tid, const f4* __restrict__ tw) {
  constexpr int G = NP / 16;
  constexpr int ST = stepFor(G);
  int i = tid & (G - 1);
  int base = (tid & ~(G - 1)) * 16 + i;
  cf* Xp = X + phys(base);
  cf v[16];
  #pragma unroll
  for (int m = 0; m < 16; ++m) v[m] = Xp[ST * m];
  dft16_f(v);
  if (G > 1) {
    if (TW) twiddle_tbl<16>(v, tw + TW_F2, i);
    else if (i) twiddle_f_chain(v, i, 1.0f / (float)NP);
  }
  #pragma unroll
  for (int s = 0; s < 16; ++s) Xp[ST * s] = v[s];
}

template<int NP, bool TW>
__device__ __forceinline__ void pass_i(cf* X, int tid, const f4* __restrict__ tw) {
  constexpr int G = NP / 16;
  constexpr int ST = stepFor(G);
  int i = tid & (G - 1);
  int base = (tid & ~(G - 1)) * 16 + i;
  cf* Xp = X + phys(base);
  cf v[16];
  #pragma unroll
  for (int s = 0; s < 16; ++s) v[s] = Xp[ST * s];
  if (G > 1) {
    if (TW) {
      if (G == 256) twiddle_tbl<256>(v, tw + TW_I1, i);
      else          twiddle_tbl<16>(v, tw + TW_I2, i);
    } else if (i) twiddle_i_chain(v, i, 1.0f / (float)NP);
  }
  dft16_i(v);
  #pragma unroll
  for (int m = 0; m < 16; ++m) Xp[ST * m] = v[m];
}

template<bool TW>
__device__ __forceinline__ void fft_forward(cf* X, int tid, const f4* __restrict__ tw) {
  pass_f_first<TW>(X, tid, tw); __syncthreads();
  pass_f<256, TW>(X, tid, tw);  __syncthreads();
  pass_f<16, TW>(X, tid, tw);   __syncthreads();
}
template<bool TW>
__device__ __forceinline__ void fft_inverse(cf* X, int tid, const f4* __restrict__ tw) {
  pass_i<16, TW>(X, tid, tw);   __syncthreads();
  pass_i<256, TW>(X, tid, tw);  __syncthreads();
  pass_i<4096, TW>(X, tid, tw); // own slots only; no trailing barrier needed
}

// rfft-halving unpack (filter kernel only)
__device__ __forceinline__ void unpack_pair(cf Zk, cf Zq, float c_, float s_,
                                            cf& Xk, cf& Xm) {
  float Ex = 0.5f*(Zk.x + Zq.x), Ey = 0.5f*(Zk.y - Zq.y);
  float Ox = 0.5f*(Zk.y + Zq.y), Oy = 0.5f*(Zq.x - Zk.x);
  Xk = cf{Ex + c_*Ox + s_*Oy,  Ey + c_*Oy - s_*Ox};
  Xm = cf{Ex - c_*Ox - s_*Oy, -Ey + c_*Oy - s_*Ox};
}

__device__ __forceinline__ cf bf16pair_to_cf(unsigned int v) {
  return cf{__uint_as_float(v << 16), __uint_as_float(v & 0xFFFF0000u)};
}
__device__ __forceinline__ unsigned int cf_to_bf16pair(cf z) {
  unsigned int a = __float_as_uint(z.x), b = __float_as_uint(z.y);
  a = (a + 0x7FFFu + ((a >> 16) & 1u)) >> 16;
  b = (b + 0x7FFFu + ((b >> 16) & 1u)) & 0xFFFF0000u;
  return a | b;
}
__device__ __forceinline__ unsigned int pack_bf16(float x, float y) {
  return cf_to_bf16pair(cf{x, y});
}

// ---------------- kernel 1: implicit filter + FFT -> G-operator table -------
//   W[k] = G1[k]*Z[k] + G2[k]*conj(Z[(4096-k)&4095])
// Extra block (c==NCH) precomputes the conv twiddle tables.
__device__ __forceinline__ float mlp_eval(int n, const float* sw1, const float* sb1,
    const float* sw2, const float* sb2, const float* sfq, const float* sw3,
    float B3, float D) {
  float t = (float)n * (1.0f / 4095.0f);
  float fw = 1e-4f * 6.283185307179586f * (float)n / 4096.0f;
  float sfw, cfw; __sincosf(fw, &sfw, &cfw);
  float z0 = t, z1 = cfw, z2 = -sfw;
  float h1[16], h2[16];
  #pragma unroll
  for (int r = 0; r < 16; ++r)
    h1[r] = __sinf(sfq[r] * (z0 * sw1[3*r] + z1 * sw1[3*r+1] + z2 * sw1[3*r+2] + sb1[r]));
  #pragma unroll
  for (int r = 0; r < 16; ++r) {
    float acc = sb2[r];
    #pragma unroll
    for (int s = 0; s < 16; ++s) acc += h1[s] * sw2[16*r + s];
    h2[r] = __sinf(sfq[r] * acc);
  }
  float k = B3;
  #pragma unroll
  for (int r = 0; r < 16; ++r) k += h2[r] * sw3[r];
  return k * __expf(-t * D);
}

__global__ __launch_bounds__(256) void filter_fft_kernel(
    const float* __restrict__ w1, const float* __restrict__ b1,
    const float* __restrict__ w2, const float* __restrict__ b2,
    const float* __restrict__ w3, const float* __restrict__ b3,
    const float* __restrict__ freq, const float* __restrict__ deltas,
    uint2* __restrict__ Kg, f4* __restrict__ Tw) {
  int tid = threadIdx.x;
  int c = blockIdx.x;

  if (c == NCH) {   // twiddle-table init block (conv runs after this kernel)
    #pragma unroll 1
    for (int r = 1; r < 16; ++r) {
      float ang = -6.283185307179586f * (float)(tid * r) / 4096.0f;
      float s, cs; sincosf(ang, &s, &cs);
      Tw[TW_F1 + (r - 1) * 256 + tid] = f4{cs, s, -s, cs};
      Tw[TW_I1 + (r - 1) * 256 + tid] = f4{cs, -s, s, cs};
    }
    if (tid < 240) {
      int r = (tid >> 4) + 1, i = tid & 15;
      float ang = -6.283185307179586f * (float)(i * r) / 256.0f;
      float s, cs; sincosf(ang, &s, &cs);
      Tw[TW_F2 + tid] = f4{cs, s, -s, cs};
      Tw[TW_I2 + tid] = f4{cs, -s, s, cs};
    }
    return;
  }

  __shared__ cf X[LDSN];
  __shared__ float sw1[48], sb1[16], sw2[256], sb2[16], sfq[16], sw3[16];
  if (tid < 48) sw1[tid] = w1[tid];
  if (tid < 16) { sb1[tid] = b1[tid]; sb2[tid] = b2[tid]; sfq[tid] = freq[tid];
                  sw3[tid] = w3[(size_t)c * 16 + tid]; }
  sw2[tid] = w2[tid];
  float B3 = b3[c], D = deltas[c];
  __syncthreads();

  {
    cf* Xp = X + phys(tid);
    #pragma unroll
    for (int j = 0; j < 8; ++j) {
      int n2 = tid + 256 * j;
      float k0 = mlp_eval(2*n2,     sw1, sb1, sw2, sb2, sfq, sw3, B3, D);
      float k1 = mlp_eval(2*n2 + 1, sw1, sb1, sw2, sb2, sfq, sw3, B3, D);
      Xp[273 * j] = cf{k0, k1};
    }
  }

  fft_forward<false>(X, tid, nullptr);

  const float SC = 1.0f / 33554432.0f;   // 1/(8192*4096)
  uint2* Kc = Kg + (size_t)c * KGST;
  for (int k = tid; k <= 2048; k += 256) {
    int q = (4096 - k) & 4095;
    cf Zk = X[phys(br12(k))], Zq = X[phys(br12(q))];
    float s_, c_; __sincosf((float)k * (3.14159265358979e0f / 4096.0f), &s_, &c_);
    cf Xk, Xm;
    unpack_pair(Zk, Zq, c_, s_, Xk, Xm);   // Xk=K[k]/SC, Xm=K[q]/SC
    float f0 = SC * 0.5f * (1.0f - s_);
    float f1 = SC * 0.5f * (1.0f + s_);
    float f2 = SC * 0.5f * c_;
    cf Xmc = cf{Xm.x, -Xm.y};
    cf Xkc = cf{Xk.x, -Xk.y};
    cf G1k = f0 * Xk + f1 * Xmc;
    cf G2k = f2 * icmul(Xk - Xmc);
    cf G1q = f0 * Xm + f1 * Xkc;
    cf G2q = -f2 * icmul(Xm - Xkc);
    Kc[k] = uint2{cf_to_bf16pair(G1k), cf_to_bf16pair(G2k)};
    Kc[q] = uint2{cf_to_bf16pair(G1q), cf_to_bf16pair(G2q)};
  }
}

// ---------------- kernel 2: u[B,L,CH] -> bf16 ut[B,CH,L], vectorized --------
__global__ __launch_bounds__(256) void transpose_in(
    const float* __restrict__ u, __hip_bfloat16* __restrict__ ut) {
  __shared__ float tile[64][65];   // [ch][L]
  int i0 = blockIdx.x * 64, c0 = blockIdx.y * 64, b = blockIdx.z;
  int tx = threadIdx.x & 15, ty = threadIdx.x >> 4;
  const float* up = u + ((size_t)b * SEQ + i0) * NCH + c0;
  #pragma unroll
  for (int rr = 0; rr < 4; ++rr) {
    int row = ty + 16 * rr;                            // local L
    f4 v = *(const f4*)&up[(size_t)row * NCH + tx * 4];
    tile[tx*4 + 0][row] = v.x;
    tile[tx*4 + 1][row] = v.y;
    tile[tx*4 + 2][row] = v.z;
    tile[tx*4 + 3][row] = v.w;
  }
  __syncthreads();
  __hip_bfloat16* op = ut + ((size_t)b * NCH + c0) * SEQ + i0;
  #pragma unroll
  for (int cp = 0; cp < 4; ++cp) {
    int c = ty + 16 * cp;                              // local ch
    uint2 o;
    o.x = pack_bf16(tile[c][tx*4 + 0], tile[c][tx*4 + 1]);
    o.y = pack_bf16(tile[c][tx*4 + 2], tile[c][tx*4 + 3]);
    *(uint2*)&op[(size_t)c * SEQ + tx * 4] = o;
  }
}

// ---------------- kernel 3: FFT conv per (channel, batch), in place ---------
// chunked XCD swizzle: each XCD owns 96 contiguous channels (3.1 MB of Kg).
__global__ __launch_bounds__(256) void conv_kernel(
    __hip_bfloat16* __restrict__ ut, const uint2* __restrict__ Kg,
    const f4* __restrict__ Tw) {
  __shared__ cf X[LDSN];
  int tid = threadIdx.x;
  int wg  = blockIdx.x;
  int id  = (wg & 7) * (NCH * NB / 8) + (wg >> 3);   // bijective: 12288 % 8 == 0
  int c   = id >> 4;
  int b   = id & 15;
  unsigned int* row = (unsigned int*)(ut + ((size_t)b * NCH + c) * SEQ);
  const uint2* Kc = Kg + (size_t)c * KGST;

  // load 4096 bf16 as 2048 packed complex into lower half (own slots only)
  {
    cf* Xp = X + phys(tid);
    #pragma unroll
    for (int j = 0; j < 8; ++j) Xp[273 * j] = bf16pair_to_cf(row[tid + 256 * j]);
  }

  fft_forward<true>(X, tid, Tw);

  // fused spectral operator: W[k] = G1[k]Z[k] + G2[k]conj(Z[q]) (and same for q)
  for (int k = tid; k <= 2048; k += 256) {
    int q  = (4096 - k) & 4095;
    int p  = phys(br12(k));
    int pq = phys(br12(q));
    cf Zk = X[p], Zq = X[pq];
    uint2 gk = Kc[k];
    uint2 gq = Kc[q];
    cf G1k = bf16pair_to_cf(gk.x), G2k = bf16pair_to_cf(gk.y);
    cf G1q = bf16pair_to_cf(gq.x), G2q = bf16pair_to_cf(gq.y);
    X[p]  = cmul(G1k, Zk) + cmul_cj(G2k, Zq);
    X[pq] = cmul(G1q, Zq) + cmul_cj(G2q, Zk);
  }
  __syncthreads();

  fft_inverse<true>(X, tid, Tw);

  // store first 4096 samples (= 2048 packed complex) — exactly one row
  {
    cf* Xp = X + phys(tid);
    #pragma unroll
    for (int j = 0; j < 8; ++j) row[tid + 256 * j] = cf_to_bf16pair(Xp[273 * j]);
  }
}

// ---------------- kernel 4: yt[B,CH,L] -> y[B,L,CH], fused + u*bias ---------
__global__ __launch_bounds__(256) void transpose_out(
    const __hip_bfloat16* __restrict__ yt, const float* __restrict__ u,
    const float* __restrict__ bias, float* __restrict__ y) {
  __shared__ float tile[64][65];   // [L][ch]
  int i0 = blockIdx.x * 64, c0 = blockIdx.y * 64, b = blockIdx.z;
  int tx = threadIdx.x & 15, ty = threadIdx.x >> 4;
  const __hip_bfloat16* ypb = yt + ((size_t)b * NCH + c0) * SEQ + i0;
  #pragma unroll
  for (int cp = 0; cp < 4; ++cp) {
    int c = ty + 16 * cp;                              // local ch
    uint2 v = *(const uint2*)&ypb[(size_t)c * SEQ + tx * 4];
    cf lo = bf16pair_to_cf(v.x), hi = bf16pair_to_cf(v.y);
    tile[tx*4 + 0][c] = lo.x;
    tile[tx*4 + 1][c] = lo.y;
    tile[tx*4 + 2][c] = hi.x;
    tile[tx*4 + 3][c] = hi.y;
  }
  __syncthreads();
  f4 bi = *(const f4*)&bias[c0 + tx * 4];
  const float* up = u + ((size_t)b * SEQ + i0) * NCH + c0;
  float* op = y + ((size_t)b * SEQ + i0) * NCH + c0;
  #pragma unroll
  for (int rp = 0; rp < 4; ++rp) {
    int row = ty + 16 * rp;                            // local L
    f4 uv = __builtin_nontemporal_load((const f4*)&up[(size_t)row * NCH + tx * 4]);
    f4 o;
    o.x = tile[row][tx*4 + 0] + uv.x * bi.x;
    o.y = tile[row][tx*4 + 1] + uv.y * bi.y;
    o.z = tile[row][tx*4 + 2] + uv.z * bi.z;
    o.w = tile[row][tx*4 + 3] + uv.w * bi.w;
    __builtin_nontemporal_store(o, (f4*)&op[(size_t)row * NCH + tx * 4]);
  }
}

extern "C" void kernel_launch(void* const* d_in, const int* in_sizes, int n_in,
                              void* d_out, int out_size, void* d_ws, size_t ws_size,
                              hipStream_t stream) {
  const float* u      = (const float*)d_in[0];
  const float* w1     = (const float*)d_in[1];
  const float* b1     = (const float*)d_in[2];
  const float* w2     = (const float*)d_in[3];
  const float* b2     = (const float*)d_in[4];
  const float* w3     = (const float*)d_in[5];
  const float* b3     = (const float*)d_in[6];
  const float* freq   = (const float*)d_in[7];
  const float* deltas = (const float*)d_in[8];
  const float* bias   = (const float*)d_in[9];
  float* out = (float*)d_out;

  const size_t utB = (size_t)NB * NCH * SEQ * 2;   // 100,663,296
  const size_t kgB = (size_t)NCH * KGST * 8;       //  25,214,976

  __hip_bfloat16* ut = (__hip_bfloat16*)d_ws;
  uint2* Kg = (uint2*)((char*)d_ws + utB);
  f4* Tw = (f4*)((char*)d_ws + utB + kgB);         // 130,560 B

  filter_fft_kernel<<<dim3(NCH + 1), dim3(256), 0, stream>>>(w1, b1, w2, b2, w3, b3, freq, deltas, Kg, Tw);
  transpose_in<<<dim3(SEQ / 64, NCH / 64, NB), dim3(256), 0, stream>>>(u, ut);
  conv_kernel<<<dim3(NCH * NB), dim3(256), 0, stream>>>(ut, Kg, Tw);
  transpose_out<<<dim3(SEQ / 64, NCH / 64, NB), dim3(256), 0, stream>>>(ut, u, bias, out);
}

// Round 14
// 437.140 us; speedup vs baseline: 1.0821x; 1.0821x over previous
//
#include <hip/hip_runtime.h>
#include <hip/hip_bf16.h>

#define SEQ   4096
#define NFFT  8192
#define NCH   768
#define NB    16
#define KGST  4104            // Kg row stride in uint2 units (4096 bins + pad)
#define LDSN  4368            // phys(4095)=4365

// packed complex float: clang lowers +,-,* to v_pk_{add,mul,fma}_f32 on gfx950
typedef float cf __attribute__((ext_vector_type(2)));
typedef float f4 __attribute__((ext_vector_type(4)));

// padding spreads both stride-16 (->17) and stride-256 (->273) lane patterns
__device__ __forceinline__ int phys(int p) { return p + (p >> 4) + (p >> 8); }
__device__ __forceinline__ int br12(int k) { return (int)(__brev((unsigned)k) >> 20); }

// phys() is affine over each pass's access set base + m*G (no carries into
// bits 4/8): phys(base + m*G) = phys(base) + m*step(G).
constexpr int stepFor(int G) { return G == 256 ? 273 : (G == 16 ? 17 : 1); }

// constexpr so BR4[r] folds at compile time -> v[] statically indexed -> regs
constexpr int BR4[16] = {0,8,4,12,2,10,6,14,1,9,5,13,3,11,7,15};

// a*w given iw = i*w:  r = a.xx*w + a.yy*iw  -> pk_mul + pk_fma
__device__ __forceinline__ cf cmul_wi(cf a, cf w, cf iw) {
  cf axx = __builtin_shufflevector(a, a, 0, 0);
  cf ayy = __builtin_shufflevector(a, a, 1, 1);
  return axx * w + ayy * iw;
}
__device__ __forceinline__ cf icmul(cf a) { return cf{-a.y, a.x}; }  // i*a
__device__ __forceinline__ cf cmul(cf a, cf b) { return cmul_wi(a, b, icmul(b)); }
// a * conj(z)
__device__ __forceinline__ cf cmul_cj(cf a, cf z) {
  return cmul_wi(a, cf{z.x, -z.y}, cf{z.y, z.x});
}

#define CMULC(a, WX, WY) cmul_wi(a, cf{(WX),(WY)}, cf{-(WY),(WX)})

#define C1X 0.9238795325112867f
#define C1Y (-0.3826834323650898f)
#define C2X 0.7071067811865476f
#define C2Y (-0.7071067811865476f)
#define C3X 0.3826834323650898f
#define C3Y (-0.9238795325112867f)

#define BF_F(a, b, WX, WY) { cf t_ = a - b; a = a + b; b = CMULC(t_, WX, WY); }
#define BF_F1(a, b)        { cf t_ = a - b; a = a + b; b = t_; }
#define BF_FJ(a, b)        { cf t_ = a - b; a = a + b; b = cf{t_.y, -t_.x}; }
#define BF_I(a, b, WX, WY) { cf t_ = cmul_wi(b, cf{(WX),-(WY)}, cf{(WY),(WX)}); b = a - t_; a = a + t_; }
#define BF_I1(a, b)        { cf t_ = b; b = a - t_; a = a + t_; }
#define BF_IJ(a, b)        { cf t_ = cf{-b.y, b.x}; b = a - t_; a = a + t_; }

__device__ __forceinline__ void dft16_f_tail(cf v[16]) {
  BF_F1(v[0], v[4]);            BF_F(v[1], v[5],  C2X, C2Y);
  BF_FJ(v[2], v[6]);            BF_F(v[3], v[7], -C2X, C2Y);
  BF_F1(v[8], v[12]);           BF_F(v[9], v[13], C2X, C2Y);
  BF_FJ(v[10], v[14]);          BF_F(v[11], v[15], -C2X, C2Y);
  BF_F1(v[0], v[2]);  BF_FJ(v[1], v[3]);
  BF_F1(v[4], v[6]);  BF_FJ(v[5], v[7]);
  BF_F1(v[8], v[10]); BF_FJ(v[9], v[11]);
  BF_F1(v[12], v[14]); BF_FJ(v[13], v[15]);
  BF_F1(v[0], v[1]);  BF_F1(v[2], v[3]);
  BF_F1(v[4], v[5]);  BF_F1(v[6], v[7]);
  BF_F1(v[8], v[9]);  BF_F1(v[10], v[11]);
  BF_F1(v[12], v[13]); BF_F1(v[14], v[15]);
}

__device__ __forceinline__ void dft16_f(cf v[16]) {
  BF_F1(v[0], v[8]);
  BF_F(v[1], v[9],  C1X, C1Y);
  BF_F(v[2], v[10], C2X, C2Y);
  BF_F(v[3], v[11], C3X, C3Y);
  BF_FJ(v[4], v[12]);
  BF_F(v[5], v[13], -C3X, C3Y);
  BF_F(v[6], v[14], -C2X, C2Y);
  BF_F(v[7], v[15], -C1X, C1Y);
  dft16_f_tail(v);
}

__device__ __forceinline__ void dft16_i(cf v[16]) {
  BF_I1(v[0], v[1]);  BF_I1(v[2], v[3]);
  BF_I1(v[4], v[5]);  BF_I1(v[6], v[7]);
  BF_I1(v[8], v[9]);  BF_I1(v[10], v[11]);
  BF_I1(v[12], v[13]); BF_I1(v[14], v[15]);
  BF_I1(v[0], v[2]);  BF_IJ(v[1], v[3]);
  BF_I1(v[4], v[6]);  BF_IJ(v[5], v[7]);
  BF_I1(v[8], v[10]); BF_IJ(v[9], v[11]);
  BF_I1(v[12], v[14]); BF_IJ(v[13], v[15]);
  BF_I1(v[0], v[4]);            BF_I(v[1], v[5],  C2X, C2Y);
  BF_IJ(v[2], v[6]);            BF_I(v[3], v[7], -C2X, C2Y);
  BF_I1(v[8], v[12]);           BF_I(v[9], v[13], C2X, C2Y);
  BF_IJ(v[10], v[14]);          BF_I(v[11], v[15], -C2X, C2Y);
  BF_I1(v[0], v[8]);
  BF_I(v[1], v[9],  C1X, C1Y);
  BF_I(v[2], v[10], C2X, C2Y);
  BF_I(v[3], v[11], C3X, C3Y);
  BF_IJ(v[4], v[12]);
  BF_I(v[5], v[13], -C3X, C3Y);
  BF_I(v[6], v[14], -C2X, C2Y);
  BF_I(v[7], v[15], -C1X, C1Y);
}

// log-depth twiddle powers: depth 4 vs 15-deep serial spine. Live regs stay
// in VGPRs (constexpr BR4 -> static indexing; occupancy is LDS-capped anyway).
__device__ __forceinline__ void twiddle_apply(cf v[16], cf w1) {
  cf iw1 = icmul(w1);
  cf w2 = cmul_wi(w1, w1, iw1),  iw2 = icmul(w2);
  cf w4 = cmul_wi(w2, w2, iw2),  iw4 = icmul(w4);
  cf w8 = cmul_wi(w4, w4, iw4),  iw8 = icmul(w8);
  cf w3 = cmul_wi(w1, w2, iw2);
  cf w5 = cmul_wi(w1, w4, iw4);
  cf w6 = cmul_wi(w2, w4, iw4);
  cf w7 = cmul_wi(w3, w4, iw4);
  cf w9  = cmul_wi(w1, w8, iw8);
  cf w10 = cmul_wi(w2, w8, iw8);
  cf w11 = cmul_wi(w3, w8, iw8);
  cf w12 = cmul_wi(w4, w8, iw8);
  cf w13 = cmul_wi(w5, w8, iw8);
  cf w14 = cmul_wi(w6, w8, iw8);
  cf w15 = cmul_wi(w7, w8, iw8);
  v[BR4[1]]  = cmul_wi(v[BR4[1]],  w1,  iw1);
  v[BR4[2]]  = cmul_wi(v[BR4[2]],  w2,  iw2);
  v[BR4[3]]  = cmul(v[BR4[3]],  w3);
  v[BR4[4]]  = cmul_wi(v[BR4[4]],  w4,  iw4);
  v[BR4[5]]  = cmul(v[BR4[5]],  w5);
  v[BR4[6]]  = cmul(v[BR4[6]],  w6);
  v[BR4[7]]  = cmul(v[BR4[7]],  w7);
  v[BR4[8]]  = cmul_wi(v[BR4[8]],  w8,  iw8);
  v[BR4[9]]  = cmul(v[BR4[9]],  w9);
  v[BR4[10]] = cmul(v[BR4[10]], w10);
  v[BR4[11]] = cmul(v[BR4[11]], w11);
  v[BR4[12]] = cmul(v[BR4[12]], w12);
  v[BR4[13]] = cmul(v[BR4[13]], w13);
  v[BR4[14]] = cmul(v[BR4[14]], w14);
  v[BR4[15]] = cmul(v[BR4[15]], w15);
}

__device__ __forceinline__ void twiddle_f(cf v[16], int i, float invNP) {
  float sn, cs; __sincosf(-6.283185307179586f * (float)i * invNP, &sn, &cs);
  twiddle_apply(v, cf{cs, sn});
}
__device__ __forceinline__ void twiddle_i(cf v[16], int i, float invNP) {
  float sn, cs; __sincosf(6.283185307179586f * (float)i * invNP, &sn, &cs);
  twiddle_apply(v, cf{cs, sn});
}

// first forward pass (NP=4096,G=256), input zero for indices >= 2048;
// touches only the calling thread's own slots {tid + m*256}
__device__ __forceinline__ void pass_f_first(cf* X, int tid) {
  cf* Xp = X + phys(tid);                  // affine: slots at 273*m
  cf v[16];
  #pragma unroll
  for (int m = 0; m < 8; ++m) v[m] = Xp[273 * m];
  v[8]  = v[0];
  v[9]  = CMULC(v[1],  C1X, C1Y);
  v[10] = CMULC(v[2],  C2X, C2Y);
  v[11] = CMULC(v[3],  C3X, C3Y);
  v[12] = cf{v[4].y, -v[4].x};
  v[13] = CMULC(v[5], -C3X, C3Y);
  v[14] = CMULC(v[6], -C2X, C2Y);
  v[15] = CMULC(v[7], -C1X, C1Y);
  dft16_f_tail(v);
  if (tid) twiddle_f(v, tid, 1.0f / 4096.0f);
  #pragma unroll
  for (int s = 0; s < 16; ++s) Xp[273 * s] = v[s];
}

template<int NP>
__device__ __forceinline__ void pass_f(cf* X, int tid) {
  constexpr int G = NP / 16;
  constexpr int ST = stepFor(G);
  int i = tid & (G - 1);
  int base = (tid & ~(G - 1)) * 16 + i;
  cf* Xp = X + phys(base);
  cf v[16];
  #pragma unroll
  for (int m = 0; m < 16; ++m) v[m] = Xp[ST * m];
  dft16_f(v);
  if (G > 1 && i) twiddle_f(v, i, 1.0f / (float)NP);
  #pragma unroll
  for (int s = 0; s < 16; ++s) Xp[ST * s] = v[s];
}

template<int NP>
__device__ __forceinline__ void pass_i(cf* X, int tid) {
  constexpr int G = NP / 16;
  constexpr int ST = stepFor(G);
  int i = tid & (G - 1);
  int base = (tid & ~(G - 1)) * 16 + i;
  cf* Xp = X + phys(base);
  cf v[16];
  #pragma unroll
  for (int s = 0; s < 16; ++s) v[s] = Xp[ST * s];
  if (G > 1 && i) twiddle_i(v, i, 1.0f / (float)NP);
  dft16_i(v);
  #pragma unroll
  for (int m = 0; m < 16; ++m) Xp[ST * m] = v[m];
}

// fill(own slots) -> pass_f_first(own slots): no leading barrier needed
__device__ __forceinline__ void fft_forward(cf* X, int tid) {
  pass_f_first(X, tid); __syncthreads();
  pass_f<256>(X, tid);  __syncthreads();
  pass_f<16>(X, tid);   __syncthreads();
}
// pass_i<4096> touches only own slots {tid+m*256}; store after it too
__device__ __forceinline__ void fft_inverse(cf* X, int tid) {
  pass_i<16>(X, tid);   __syncthreads();
  pass_i<256>(X, tid);  __syncthreads();
  pass_i<4096>(X, tid);
}

// rfft-halving unpack (filter kernel only)
__device__ __forceinline__ void unpack_pair(cf Zk, cf Zq, float c_, float s_,
                                            cf& Xk, cf& Xm) {
  float Ex = 0.5f*(Zk.x + Zq.x), Ey = 0.5f*(Zk.y - Zq.y);
  float Ox = 0.5f*(Zk.y + Zq.y), Oy = 0.5f*(Zq.x - Zk.x);
  Xk = cf{Ex + c_*Ox + s_*Oy,  Ey + c_*Oy - s_*Ox};
  Xm = cf{Ex - c_*Ox - s_*Oy, -Ey + c_*Oy - s_*Ox};
}

__device__ __forceinline__ cf bf16pair_to_cf(unsigned int v) {
  return cf{__uint_as_float(v << 16), __uint_as_float(v & 0xFFFF0000u)};
}
__device__ __forceinline__ unsigned int cf_to_bf16pair(cf z) {
  unsigned int a = __float_as_uint(z.x), b = __float_as_uint(z.y);
  a = (a + 0x7FFFu + ((a >> 16) & 1u)) >> 16;
  b = (b + 0x7FFFu + ((b >> 16) & 1u)) & 0xFFFF0000u;
  return a | b;
}
__device__ __forceinline__ unsigned int pack_bf16(float x, float y) {
  return cf_to_bf16pair(cf{x, y});
}

// ---------------- kernel 1: implicit filter + FFT -> G-operator table -------
//   W[k] = G1[k]*Z[k] + G2[k]*conj(Z[(4096-k)&4095])
//   G1[k] = ((1-s)/2)K[k] + ((1+s)/2)K*[q],  G2[k] = (i c/2)(K[k]-K*[q])
__device__ __forceinline__ float mlp_eval(int n, const float* sw1, const float* sb1,
    const float* sw2, const float* sb2, const float* sfq, const float* sw3,
    float B3, float D) {
  float t = (float)n * (1.0f / 4095.0f);
  float fw = 1e-4f * 6.283185307179586f * (float)n / 4096.0f;
  float sfw, cfw; __sincosf(fw, &sfw, &cfw);
  float z0 = t, z1 = cfw, z2 = -sfw;
  float h1[16], h2[16];
  #pragma unroll
  for (int r = 0; r < 16; ++r)
    h1[r] = __sinf(sfq[r] * (z0 * sw1[3*r] + z1 * sw1[3*r+1] + z2 * sw1[3*r+2] + sb1[r]));
  #pragma unroll
  for (int r = 0; r < 16; ++r) {
    float acc = sb2[r];
    #pragma unroll
    for (int s = 0; s < 16; ++s) acc += h1[s] * sw2[16*r + s];
    h2[r] = __sinf(sfq[r] * acc);
  }
  float k = B3;
  #pragma unroll
  for (int r = 0; r < 16; ++r) k += h2[r] * sw3[r];
  return k * __expf(-t * D);
}

__global__ __launch_bounds__(256) void filter_fft_kernel(
    const float* __restrict__ w1, const float* __restrict__ b1,
    const float* __restrict__ w2, const float* __restrict__ b2,
    const float* __restrict__ w3, const float* __restrict__ b3,
    const float* __restrict__ freq, const float* __restrict__ deltas,
    uint2* __restrict__ Kg) {
  __shared__ cf X[LDSN];
  __shared__ float sw1[48], sb1[16], sw2[256], sb2[16], sfq[16], sw3[16];
  int tid = threadIdx.x;
  int c = blockIdx.x;
  if (tid < 48) sw1[tid] = w1[tid];
  if (tid < 16) { sb1[tid] = b1[tid]; sb2[tid] = b2[tid]; sfq[tid] = freq[tid];
                  sw3[tid] = w3[(size_t)c * 16 + tid]; }
  sw2[tid] = w2[tid];
  float B3 = b3[c], D = deltas[c];
  __syncthreads();

  {
    cf* Xp = X + phys(tid);
    #pragma unroll
    for (int j = 0; j < 8; ++j) {
      int n2 = tid + 256 * j;
      float k0 = mlp_eval(2*n2,     sw1, sb1, sw2, sb2, sfq, sw3, B3, D);
      float k1 = mlp_eval(2*n2 + 1, sw1, sb1, sw2, sb2, sfq, sw3, B3, D);
      Xp[273 * j] = cf{k0, k1};
    }
  }

  fft_forward(X, tid);

  const float SC = 1.0f / 33554432.0f;   // 1/(8192*4096)
  uint2* Kc = Kg + (size_t)c * KGST;
  for (int k = tid; k <= 2048; k += 256) {
    int q = (4096 - k) & 4095;
    cf Zk = X[phys(br12(k))], Zq = X[phys(br12(q))];
    float s_, c_; __sincosf((float)k * (3.14159265358979e0f / 4096.0f), &s_, &c_);
    cf Xk, Xm;
    unpack_pair(Zk, Zq, c_, s_, Xk, Xm);   // Xk=K[k]/SC, Xm=K[q]/SC
    float f0 = SC * 0.5f * (1.0f - s_);
    float f1 = SC * 0.5f * (1.0f + s_);
    float f2 = SC * 0.5f * c_;
    cf Xmc = cf{Xm.x, -Xm.y};
    cf Xkc = cf{Xk.x, -Xk.y};
    cf G1k = f0 * Xk + f1 * Xmc;
    cf G2k = f2 * icmul(Xk - Xmc);
    cf G1q = f0 * Xm + f1 * Xkc;
    cf G2q = -f2 * icmul(Xm - Xkc);
    Kc[k] = uint2{cf_to_bf16pair(G1k), cf_to_bf16pair(G2k)};
    Kc[q] = uint2{cf_to_bf16pair(G1q), cf_to_bf16pair(G2q)};
  }
}

// ---------------- kernel 2: u[B,L,CH] -> bf16 ut[B,CH,L], vectorized --------
__global__ __launch_bounds__(256) void transpose_in(
    const float* __restrict__ u, __hip_bfloat16* __restrict__ ut) {
  __shared__ float tile[64][65];   // [ch][L]
  int i0 = blockIdx.x * 64, c0 = blockIdx.y * 64, b = blockIdx.z;
  int tx = threadIdx.x & 15, ty = threadIdx.x >> 4;
  const float* up = u + ((size_t)b * SEQ + i0) * NCH + c0;
  #pragma unroll
  for (int rr = 0; rr < 4; ++rr) {
    int row = ty + 16 * rr;                            // local L
    f4 v = *(const f4*)&up[(size_t)row * NCH + tx * 4];
    tile[tx*4 + 0][row] = v.x;
    tile[tx*4 + 1][row] = v.y;
    tile[tx*4 + 2][row] = v.z;
    tile[tx*4 + 3][row] = v.w;
  }
  __syncthreads();
  __hip_bfloat16* op = ut + ((size_t)b * NCH + c0) * SEQ + i0;
  #pragma unroll
  for (int cp = 0; cp < 4; ++cp) {
    int c = ty + 16 * cp;                              // local ch
    uint2 o;
    o.x = pack_bf16(tile[c][tx*4 + 0], tile[c][tx*4 + 1]);
    o.y = pack_bf16(tile[c][tx*4 + 2], tile[c][tx*4 + 3]);
    *(uint2*)&op[(size_t)c * SEQ + tx * 4] = o;
  }
}

// ---------------- kernel 3: FFT conv per (channel, batch), in place ---------
// chunked XCD swizzle: each XCD owns 96 contiguous channels (3.1 MB of Kg).
__global__ __launch_bounds__(256) void conv_kernel(
    __hip_bfloat16* __restrict__ ut, const uint2* __restrict__ Kg) {
  __shared__ cf X[LDSN];
  int tid = threadIdx.x;
  int wg  = blockIdx.x;
  int id  = (wg & 7) * (NCH * NB / 8) + (wg >> 3);   // bijective: 12288 % 8 == 0
  int c   = id >> 4;
  int b   = id & 15;
  unsigned int* row = (unsigned int*)(ut + ((size_t)b * NCH + c) * SEQ);
  const uint2* Kc = Kg + (size_t)c * KGST;

  // load 4096 bf16 as 2048 packed complex into lower half (own slots only)
  {
    cf* Xp = X + phys(tid);
    #pragma unroll
    for (int j = 0; j < 8; ++j) Xp[273 * j] = bf16pair_to_cf(row[tid + 256 * j]);
  }

  fft_forward(X, tid);

  // fused spectral operator: W[k] = G1[k]Z[k] + G2[k]conj(Z[q]) (and same for q)
  for (int k = tid; k <= 2048; k += 256) {
    int q  = (4096 - k) & 4095;
    int p  = phys(br12(k));
    int pq = phys(br12(q));
    cf Zk = X[p], Zq = X[pq];
    uint2 gk = Kc[k];
    uint2 gq = Kc[q];
    cf G1k = bf16pair_to_cf(gk.x), G2k = bf16pair_to_cf(gk.y);
    cf G1q = bf16pair_to_cf(gq.x), G2q = bf16pair_to_cf(gq.y);
    X[p]  = cmul(G1k, Zk) + cmul_cj(G2k, Zq);
    X[pq] = cmul(G1q, Zq) + cmul_cj(G2q, Zk);
  }
  __syncthreads();

  fft_inverse(X, tid);

  // store first 4096 samples (= 2048 packed complex) — exactly one row
  {
    cf* Xp = X + phys(tid);
    #pragma unroll
    for (int j = 0; j < 8; ++j) row[tid + 256 * j] = cf_to_bf16pair(Xp[273 * j]);
  }
}

// ---------------- kernel 4: yt[B,CH,L] -> y[B,L,CH], fused + u*bias ---------
__global__ __launch_bounds__(256) void transpose_out(
    const __hip_bfloat16* __restrict__ yt, const float* __restrict__ u,
    const float* __restrict__ bias, float* __restrict__ y) {
  __shared__ float tile[64][65];   // [L][ch]
  int i0 = blockIdx.x * 64, c0 = blockIdx.y * 64, b = blockIdx.z;
  int tx = threadIdx.x & 15, ty = threadIdx.x >> 4;
  const __hip_bfloat16* ypb = yt + ((size_t)b * NCH + c0) * SEQ + i0;
  #pragma unroll
  for (int cp = 0; cp < 4; ++cp) {
    int c = ty + 16 * cp;                              // local ch
    uint2 v = *(const uint2*)&ypb[(size_t)c * SEQ + tx * 4];
    cf lo = bf16pair_to_cf(v.x), hi = bf16pair_to_cf(v.y);
    tile[tx*4 + 0][c] = lo.x;
    tile[tx*4 + 1][c] = lo.y;
    tile[tx*4 + 2][c] = hi.x;
    tile[tx*4 + 3][c] = hi.y;
  }
  __syncthreads();
  f4 bi = *(const f4*)&bias[c0 + tx * 4];
  const float* up = u + ((size_t)b * SEQ + i0) * NCH + c0;
  float* op = y + ((size_t)b * SEQ + i0) * NCH + c0;
  #pragma unroll
  for (int rp = 0; rp < 4; ++rp) {
    int row = ty + 16 * rp;                            // local L
    f4 uv = __builtin_nontemporal_load((const f4*)&up[(size_t)row * NCH + tx * 4]);
    f4 o;
    o.x = tile[row][tx*4 + 0] + uv.x * bi.x;
    o.y = tile[row][tx*4 + 1] + uv.y * bi.y;
    o.z = tile[row][tx*4 + 2] + uv.z * bi.z;
    o.w = tile[row][tx*4 + 3] + uv.w * bi.w;
    __builtin_nontemporal_store(o, (f4*)&op[(size_t)row * NCH + tx * 4]);
  }
}

extern "C" void kernel_launch(void* const* d_in, const int* in_sizes, int n_in,
                              void* d_out, int out_size, void* d_ws, size_t ws_size,
                              hipStream_t stream) {
  const float* u      = (const float*)d_in[0];
  const float* w1     = (const float*)d_in[1];
  const float* b1     = (const float*)d_in[2];
  const float* w2     = (const float*)d_in[3];
  const float* b2     = (const float*)d_in[4];
  const float* w3     = (const float*)d_in[5];
  const float* b3     = (const float*)d_in[6];
  const float* freq   = (const float*)d_in[7];
  const float* deltas = (const float*)d_in[8];
  const float* bias   = (const float*)d_in[9];
  float* out = (float*)d_out;

  const size_t utB = (size_t)NB * NCH * SEQ * 2;   // 100,663,296
  __hip_bfloat16* ut = (__hip_bfloat16*)d_ws;
  uint2* Kg = (uint2*)((char*)d_ws + utB);         // 25,214,976

  filter_fft_kernel<<<dim3(NCH), dim3(256), 0, stream>>>(w1, b1, w2, b2, w3, b3, freq, deltas, Kg);
  transpose_in<<<dim3(SEQ / 64, NCH / 64, NB), dim3(256), 0, stream>>>(u, ut);
  conv_kernel<<<dim3(NCH * NB), dim3(256), 0, stream>>>(ut, Kg);
  transpose_out<<<dim3(SEQ / 64, NCH / 64, NB), dim3(256), 0, stream>>>(ut, u, bias, out);
}